// Round 3
// baseline (181.412 us; speedup 1.0000x reference)
//
#include <hip/hip_runtime.h>

typedef unsigned short u16;
typedef unsigned int u32;
typedef __attribute__((ext_vector_type(8))) short bf16x8;
typedef __attribute__((ext_vector_type(4))) float floatx4;

__device__ __forceinline__ float bf2f(u16 u){ union{u32 i; float f;}v; v.i=((u32)u)<<16; return v.f; }
__device__ __forceinline__ float bflo(u32 u){ union{u32 i; float f;}v; v.i=u<<16; return v.f; }
__device__ __forceinline__ float bfhi(u32 u){ union{u32 i; float f;}v; v.i=u&0xFFFF0000u; return v.f; }
__device__ __forceinline__ u16 f2bf(float f){
    union{float f;u32 i;}v; v.f=f; u32 r=v.i+0x7FFFu+((v.i>>16)&1u); return (u16)(r>>16);
}
// pack two fp32 -> two bf16 (RNE) in one u32: {a lo16, b hi16} via v_perm_b32
__device__ __forceinline__ u32 pkbf(float a, float b){
    union{float f;u32 i;}x,y; x.f=a; y.f=b;
    u32 ai = x.i + 0x7FFFu + ((x.i>>16)&1u);
    u32 bi = y.i + 0x7FFFu + ((y.i>>16)&1u);
    return __builtin_amdgcn_perm(bi, ai, 0x07060302);
}

#define DD 512
#define NTOK 128

// ---------------------------------------------------------------------------
// Transposes (fp32 -> bf16). z=0: W1[0:512]->W1aT; z=1: W1[512:1024]->W1bT;
// z=2: W2(512x256)->W2T(256x512).
// ---------------------------------------------------------------------------
__global__ __launch_bounds__(256) void transpose_k(
    const float* __restrict__ W1, const float* __restrict__ W2,
    u16* __restrict__ W1aT, u16* __restrict__ W1bT, u16* __restrict__ W2T)
{
    const int z = blockIdx.z;
    const float* src; u16* dst; int rows, cols;
    if (z == 0)      { src = W1;             dst = W1aT; rows = 512; cols = 512; }
    else if (z == 1) { src = W1 + 512 * 512; dst = W1bT; rows = 512; cols = 512; }
    else             { src = W2;             dst = W2T;  rows = 512; cols = 256; }
    const int c0 = blockIdx.x * 32, r0 = blockIdx.y * 32;
    if (c0 >= cols || r0 >= rows) return;
    __shared__ u16 tile[32][33];
    const int tx = threadIdx.x & 31, ty = threadIdx.x >> 5;
#pragma unroll
    for (int i = 0; i < 4; ++i) {
        int r = ty + i * 8;
        tile[r][tx] = f2bf(src[(size_t)(r0 + r) * cols + (c0 + tx)]);
    }
    __syncthreads();
#pragma unroll
    for (int i = 0; i < 4; ++i) {
        int r = ty + i * 8;
        dst[(size_t)(c0 + r) * rows + (r0 + tx)] = tile[tx][r];
    }
}

// ---------------------------------------------------------------------------
// Layer-1 GEMM. 64x64 tiles, 256 blocks (16M x 8N x 2z), 256 thr = 4 waves 2x2,
// wave tile 32x32. Reads fp32 features directly (converts in staging).
// z=0 adds b1 into output (Hf1b); z=1 -> Hf2.
// ---------------------------------------------------------------------------
__global__ __launch_bounds__(256) void gemm_layer1(
    const float* __restrict__ features, const u16* __restrict__ W1T,
    const float* __restrict__ b1, u16* __restrict__ Hf1b, u16* __restrict__ Hf2)
{
    const int bM = blockIdx.x, bN = blockIdx.y, z = blockIdx.z;
    const u16* Bt = W1T + (size_t)z * 512 * 512;
    u16* outp = z ? Hf2 : Hf1b;
    __shared__ __align__(16) u16 At[64 * 64];
    __shared__ __align__(16) u16 Btl[64 * 64];
    const int tid = threadIdx.x;
    const int wid = tid >> 6, lane = tid & 63, lrow = lane & 15, quad = lane >> 4;
    const int wm = wid >> 1, wn = wid & 1;

    floatx4 acc[2][2];
#pragma unroll
    for (int i = 0; i < 2; ++i)
#pragma unroll
        for (int j = 0; j < 2; ++j) acc[i][j] = (floatx4)(0.0f);

    const int m = tid >> 2, seg = tid & 3, sw = m & 7;
    for (int kc = 0; kc < 8; ++kc) {
        const int k0 = kc * 64;
        {   // stage A: fp32 -> bf16, XOR-swizzled
            const float4* src = (const float4*)(features + (size_t)(bM * 64 + m) * DD + k0 + seg * 16);
            float4 f0 = src[0], f1 = src[1], f2 = src[2], f3 = src[3];
            *(uint4*)(At + m * 64 + (((seg * 2    ) ^ sw) << 3)) =
                make_uint4(pkbf(f0.x, f0.y), pkbf(f0.z, f0.w), pkbf(f1.x, f1.y), pkbf(f1.z, f1.w));
            *(uint4*)(At + m * 64 + (((seg * 2 + 1) ^ sw) << 3)) =
                make_uint4(pkbf(f2.x, f2.y), pkbf(f2.z, f2.w), pkbf(f3.x, f3.y), pkbf(f3.z, f3.w));
        }
        {   // stage B (bf16)
            const uint4* src = (const uint4*)(Bt + (size_t)(bN * 64 + m) * DD + k0 + seg * 16);
            *(uint4*)(Btl + m * 64 + (((seg * 2    ) ^ sw) << 3)) = src[0];
            *(uint4*)(Btl + m * 64 + (((seg * 2 + 1) ^ sw) << 3)) = src[1];
        }
        __syncthreads();
#pragma unroll
        for (int ks = 0; ks < 2; ++ks) {
            const int ch = ks * 4 + quad;
            bf16x8 afr[2], bfr[2];
#pragma unroll
            for (int i = 0; i < 2; ++i) {
                int r = wm * 32 + i * 16 + lrow;
                afr[i] = *(const bf16x8*)(At + r * 64 + ((ch ^ (r & 7)) << 3));
            }
#pragma unroll
            for (int j = 0; j < 2; ++j) {
                int c = wn * 32 + j * 16 + lrow;
                bfr[j] = *(const bf16x8*)(Btl + c * 64 + ((ch ^ (c & 7)) << 3));
            }
#pragma unroll
            for (int i = 0; i < 2; ++i)
#pragma unroll
                for (int j = 0; j < 2; ++j)
                    acc[i][j] = __builtin_amdgcn_mfma_f32_16x16x32_bf16(afr[i], bfr[j], acc[i][j], 0, 0, 0);
        }
        __syncthreads();
    }
#pragma unroll
    for (int j = 0; j < 2; ++j) {
        int col = bN * 64 + wn * 32 + j * 16 + lrow;
        float bb = z ? 0.0f : b1[col];
#pragma unroll
        for (int i = 0; i < 2; ++i)
#pragma unroll
            for (int r = 0; r < 4; ++r) {
                int row = bM * 64 + wm * 32 + i * 16 + quad * 4 + r;
                outp[(size_t)row * DD + col] = f2bf(acc[i][j][r] + bb);
            }
    }
}

// ---------------------------------------------------------------------------
// Fused main: one block per (n,b), 512 thr = 8 waves.
// Stage A built by per-wave P-mfma (rank-3: [px,py,1]x[c0,c1,s1]) + hf2 + relu.
// Main GEMM: A from swizzled LDS, B (W2T) straight from global (L2-hot).
// Epilogue: relu(acc+b2) -> LDS bf16 halves -> layer-3 MFMA vs padded W3.
// ---------------------------------------------------------------------------
__global__ __launch_bounds__(512, 4) void fused_main(
    const u16* __restrict__ Hf1b, const u16* __restrict__ Hf2,
    const u16* __restrict__ W2T, const float* __restrict__ W1,
    const float* __restrict__ b2, const float* __restrict__ W3,
    const float* __restrict__ b3, const float* __restrict__ positions,
    float* __restrict__ out)
{
    const int n = blockIdx.x, b = blockIdx.y;
    const int tid = threadIdx.x;
    const int base_bn = b * NTOK + n;
    const int wid = tid >> 6, lane = tid & 63, lrow = lane & 15, quad = lane >> 4;

    __shared__ __align__(16) u16 coefq[DD * 4];   // per k: {c0,c1,s1,0} bf16  (4 KB)
    __shared__ __align__(16) u16 w3t[16 * 264];   // [col16][k256+pad] bf16   (8.25 KB)
    __shared__ __align__(16) char mbuf[34816];    // Atile (16K) | gh (34K)
    u16* Atile = (u16*)mbuf;                      // [128][64] swizzled
    u16* gh    = (u16*)mbuf;                      // [128][136]

    // ---- phase 0 ----
    {   // coefq
        int k = tid;
        float c0 = W1[(size_t)1024 * DD + k];
        float c1 = W1[(size_t)1025 * DD + k];
        u16 s1 = Hf1b[(size_t)base_bn * DD + k];  // b1 already folded in
        *(uint2*)(coefq + k * 4) = make_uint2(pkbf(c0, c1), (u32)s1);
    }
    {   // w3t: W3 transposed, padded to 16 cols, bf16
        int c = tid & 15, kb = tid >> 4;          // kb 0..31
        int k0w = kb * 8;
        u32 wv[4];
#pragma unroll
        for (int p = 0; p < 4; ++p) {
            int ka = k0w + p * 2;
            u16 va = (c < 4) ? f2bf(W3[ka * 4 + c])       : (u16)0;
            u16 vb = (c < 4) ? f2bf(W3[(ka + 1) * 4 + c]) : (u16)0;
            wv[p] = (u32)va | ((u32)vb << 16);
        }
        *(uint2*)(w3t + c * 264 + k0w)     = make_uint2(wv[0], wv[1]);
        *(uint2*)(w3t + c * 264 + k0w + 4) = make_uint2(wv[2], wv[3]);
    }
    const int smrow = wid * 16;                    // stage-A / epilogue m-tile base
    bf16x8 pqf;                                    // B'-operand frag: {px,py,1,0,...}
    {
        union { bf16x8 v; u32 u[4]; } t;
        float pnx = positions[(size_t)base_bn * 2 + 0];
        float pny = positions[(size_t)base_bn * 2 + 1];
        int mg = b * NTOK + smrow + lrow;
        float pmx = positions[(size_t)mg * 2 + 0];
        float pmy = positions[(size_t)mg * 2 + 1];
        t.u[0] = (quad == 0) ? pkbf(pnx - pmx, pny - pmy) : 0u;
        t.u[1] = (quad == 0) ? 0x00003F80u : 0u;   // {bf16(1.0), 0}
        t.u[2] = 0u; t.u[3] = 0u;
        pqf = t.v;
    }
    __syncthreads();

    const int wm = wid >> 2, wn = wid & 3;         // main-GEMM 2x4 wave grid
    floatx4 acc[4][4];
#pragma unroll
    for (int i = 0; i < 4; ++i)
#pragma unroll
        for (int j = 0; j < 4; ++j) acc[i][j] = (floatx4)(0.0f);

    const u16* hf2row = Hf2 + (size_t)(b * NTOK + smrow + lrow) * DD;
    const int mA = smrow + lrow, swA = mA & 7;

    // ---- K loop ----
    for (int kc = 0; kc < 8; ++kc) {
        const int k0 = kc * 64;
        // build H tile rows [smrow, smrow+16) x k [k0, k0+64) via 4 P-mfmas
#pragma unroll
        for (int t4 = 0; t4 < 4; ++t4) {
            const int kk = t4 * 16;
            uint2 cf = *(const uint2*)(coefq + (k0 + kk + lrow) * 4);
            union { bf16x8 v; u32 u[4]; } af;
            af.u[0] = cf.x; af.u[1] = cf.y; af.u[2] = 0u; af.u[3] = 0u;
            floatx4 p = __builtin_amdgcn_mfma_f32_16x16x32_bf16(af.v, pqf, (floatx4)(0.0f), 0, 0, 0);
            uint2 hv = *(const uint2*)(hf2row + k0 + kk + quad * 4);
            float h0 = fmaxf(p[0] + bflo(hv.x), 0.0f);
            float h1 = fmaxf(p[1] + bfhi(hv.x), 0.0f);
            float h2 = fmaxf(p[2] + bflo(hv.y), 0.0f);
            float h3 = fmaxf(p[3] + bfhi(hv.y), 0.0f);
            const int kl = kk + quad * 4;
            const int chunk = kl >> 3, off = kl & 7;
            *(uint2*)(Atile + mA * 64 + ((chunk ^ swA) << 3) + off)
                = make_uint2(pkbf(h0, h1), pkbf(h2, h3));
        }
        __syncthreads();
#pragma unroll
        for (int ks = 0; ks < 2; ++ks) {
            const int ch = ks * 4 + quad;
            bf16x8 afr[4], bfr[4];
#pragma unroll
            for (int i = 0; i < 4; ++i) {
                int r = wm * 64 + i * 16 + lrow;
                afr[i] = *(const bf16x8*)(Atile + r * 64 + ((ch ^ (r & 7)) << 3));
            }
#pragma unroll
            for (int j = 0; j < 4; ++j) {
                int c = wn * 64 + j * 16 + lrow;
                bfr[j] = *(const bf16x8*)(W2T + (size_t)c * DD + k0 + ks * 32 + quad * 8);
            }
#pragma unroll
            for (int i = 0; i < 4; ++i)
#pragma unroll
                for (int j = 0; j < 4; ++j)
                    acc[i][j] = __builtin_amdgcn_mfma_f32_16x16x32_bf16(afr[i], bfr[j], acc[i][j], 0, 0, 0);
        }
        __syncthreads();
    }

    // ---- epilogue ----
    float b2v[4];
#pragma unroll
    for (int j = 0; j < 4; ++j) b2v[j] = b2[wn * 64 + j * 16 + lrow];

    floatx4 acc3 = (floatx4)(0.0f);
#pragma unroll
    for (int half = 0; half < 2; ++half) {
        __syncthreads();    // prior mbuf readers done
        if ((wn >> 1) == half) {
#pragma unroll
            for (int i = 0; i < 4; ++i)
#pragma unroll
                for (int j = 0; j < 4; ++j)
#pragma unroll
                    for (int r = 0; r < 4; ++r) {
                        int row = wm * 64 + i * 16 + quad * 4 + r;
                        int col = (wn & 1) * 64 + j * 16 + lrow;
                        gh[row * 136 + col] = f2bf(fmaxf(acc[i][j][r] + b2v[j], 0.0f));
                    }
        }
        __syncthreads();
        // layer-3: each wave does rows [smrow, smrow+16), K=128 of this half
#pragma unroll
        for (int ks = 0; ks < 4; ++ks) {
            bf16x8 gfrag = *(const bf16x8*)(gh + (smrow + lrow) * 136 + ks * 32 + quad * 8);
            bf16x8 wfrag = *(const bf16x8*)(w3t + lrow * 264 + half * 128 + ks * 32 + quad * 8);
            acc3 = __builtin_amdgcn_mfma_f32_16x16x32_bf16(gfrag, wfrag, acc3, 0, 0, 0);
        }
    }
    if (lrow < 4) {
        float bo = b3[lrow];
#pragma unroll
        for (int r = 0; r < 4; ++r) {
            int row = smrow + quad * 4 + r;
            out[(size_t)base_bn * 512 + row * 4 + lrow] = acc3[r] + bo;
        }
    }
}

// ---------------------------------------------------------------------------
extern "C" void kernel_launch(void* const* d_in, const int* in_sizes, int n_in,
                              void* d_out, int out_size, void* d_ws, size_t ws_size,
                              hipStream_t stream)
{
    const float* features  = (const float*)d_in[0];
    const float* positions = (const float*)d_in[1];
    const float* W1 = (const float*)d_in[2];
    const float* b1 = (const float*)d_in[3];
    const float* W2 = (const float*)d_in[4];
    const float* b2 = (const float*)d_in[5];
    const float* W3 = (const float*)d_in[6];
    const float* b3 = (const float*)d_in[7];
    float* out = (float*)d_out;

    char* ws = (char*)d_ws;
    u16* W1aT = (u16*)(ws);                 // 524288 B
    u16* W1bT = (u16*)(ws + 524288);        // 524288 B
    u16* W2T  = (u16*)(ws + 1048576);       // 262144 B
    u16* Hf1b = (u16*)(ws + 1310720);       // 1048576 B
    u16* Hf2  = (u16*)(ws + 2359296);       // 1048576 B (total 3.25 MB)

    transpose_k<<<dim3(16, 16, 3), 256, 0, stream>>>(W1, W2, W1aT, W1bT, W2T);
    gemm_layer1<<<dim3(16, 8, 2), 256, 0, stream>>>(features, W1aT, b1, Hf1b, Hf2);
    fused_main<<<dim3(128, 8), 512, 0, stream>>>(Hf1b, Hf2, W2T, W1, b2, W3, b3,
                                                 positions, out);
}

// Round 4
// 131.213 us; speedup vs baseline: 1.3826x; 1.3826x over previous
//
#include <hip/hip_runtime.h>
#include <hip/hip_bf16.h>

typedef unsigned short u16;
typedef unsigned int u32;
typedef __attribute__((ext_vector_type(8))) short bf16x8;
typedef __attribute__((ext_vector_type(4))) float floatx4;

__device__ __forceinline__ float bflo(u32 u){ union{u32 i; float f;}v; v.i=u<<16; return v.f; }
__device__ __forceinline__ float bfhi(u32 u){ union{u32 i; float f;}v; v.i=u&0xFFFF0000u; return v.f; }
__device__ __forceinline__ u16 f2bf(float f){
    union{float f;u32 i;}v; v.f=f; u32 r=v.i+0x7FFFu+((v.i>>16)&1u); return (u16)(r>>16);
}
// pack two fp32 -> u32 {a lo16, b hi16}, RNE (HW v_cvt_pk_bf16_f32 when available)
__device__ __forceinline__ u32 pkbf(float a, float b){
    union { __hip_bfloat162 h; u32 u; } cv;
    cv.h = __float22bfloat162_rn(float2{a, b});
    return cv.u;
}

#define DD 512
#define NTOK 128

// ---------------------------------------------------------------------------
// Transposes (fp32 -> bf16). z=0: W1[0:512]->W1aT; z=1: W1[512:1024]->W1bT;
// z=2: W2(512x256)->W2T(256x512).
// ---------------------------------------------------------------------------
__global__ __launch_bounds__(256) void transpose_k(
    const float* __restrict__ W1, const float* __restrict__ W2,
    u16* __restrict__ W1aT, u16* __restrict__ W1bT, u16* __restrict__ W2T)
{
    const int z = blockIdx.z;
    const float* src; u16* dst; int rows, cols;
    if (z == 0)      { src = W1;             dst = W1aT; rows = 512; cols = 512; }
    else if (z == 1) { src = W1 + 512 * 512; dst = W1bT; rows = 512; cols = 512; }
    else             { src = W2;             dst = W2T;  rows = 512; cols = 256; }
    const int c0 = blockIdx.x * 32, r0 = blockIdx.y * 32;
    if (c0 >= cols || r0 >= rows) return;
    __shared__ u16 tile[32][33];
    const int tx = threadIdx.x & 31, ty = threadIdx.x >> 5;
#pragma unroll
    for (int i = 0; i < 4; ++i) {
        int r = ty + i * 8;
        tile[r][tx] = f2bf(src[(size_t)(r0 + r) * cols + (c0 + tx)]);
    }
    __syncthreads();
#pragma unroll
    for (int i = 0; i < 4; ++i) {
        int r = ty + i * 8;
        dst[(size_t)(c0 + r) * rows + (r0 + tx)] = tile[tx][r];
    }
}

// ---------------------------------------------------------------------------
// Layer-1 GEMM: 64x64 tiles, grid (16M x 8N x 2z) = 256 blocks, 512 thr = 8
// waves (4 wm x 2 wn), wave tile 16x32. Reads fp32 features (converts in
// staging). z=0 folds b1 into output (Hf1b); z=1 -> Hf2.
// ---------------------------------------------------------------------------
__global__ __launch_bounds__(512) void gemm_layer1(
    const float* __restrict__ features, const u16* __restrict__ W1T,
    const float* __restrict__ b1, u16* __restrict__ Hf1b, u16* __restrict__ Hf2)
{
    const int bM = blockIdx.x, bN = blockIdx.y, z = blockIdx.z;
    const u16* Bt = W1T + (size_t)z * 512 * 512;
    u16* outp = z ? Hf2 : Hf1b;
    __shared__ __align__(16) u16 At[64 * 64];
    __shared__ __align__(16) u16 Btl[64 * 64];
    const int tid = threadIdx.x;
    const int wid = tid >> 6, lane = tid & 63, lrow = lane & 15, quad = lane >> 4;
    const int wm = wid >> 1, wn = wid & 1;

    floatx4 acc[2];
    acc[0] = (floatx4)(0.0f); acc[1] = (floatx4)(0.0f);

    const int m = tid >> 3, seg = tid & 7, sw = m & 7;
    for (int kc = 0; kc < 8; ++kc) {
        const int k0 = kc * 64;
        {   // stage A: 8 fp32 -> 8 bf16, one uint4, XOR-swizzled
            const float4* src = (const float4*)(features + (size_t)(bM * 64 + m) * DD + k0 + seg * 8);
            float4 f0 = src[0], f1 = src[1];
            *(uint4*)(At + m * 64 + ((seg ^ sw) << 3)) =
                make_uint4(pkbf(f0.x, f0.y), pkbf(f0.z, f0.w), pkbf(f1.x, f1.y), pkbf(f1.z, f1.w));
        }
        {   // stage B: 8 bf16, one uint4
            *(uint4*)(Btl + m * 64 + ((seg ^ sw) << 3)) =
                *(const uint4*)(Bt + (size_t)(bN * 64 + m) * DD + k0 + seg * 8);
        }
        __syncthreads();
#pragma unroll
        for (int ks = 0; ks < 2; ++ks) {
            const int ch = ks * 4 + quad;
            int r = wm * 16 + lrow;
            bf16x8 afr = *(const bf16x8*)(At + r * 64 + ((ch ^ (r & 7)) << 3));
#pragma unroll
            for (int j = 0; j < 2; ++j) {
                int c = wn * 32 + j * 16 + lrow;
                bf16x8 bfr = *(const bf16x8*)(Btl + c * 64 + ((ch ^ (c & 7)) << 3));
                acc[j] = __builtin_amdgcn_mfma_f32_16x16x32_bf16(afr, bfr, acc[j], 0, 0, 0);
            }
        }
        __syncthreads();
    }
#pragma unroll
    for (int j = 0; j < 2; ++j) {
        int col = bN * 64 + wn * 32 + j * 16 + lrow;
        float bb = z ? 0.0f : b1[col];
#pragma unroll
        for (int r = 0; r < 4; ++r) {
            int row = bM * 64 + wm * 16 + quad * 4 + r;
            outp[(size_t)row * DD + col] = f2bf(acc[j][r] + bb);
        }
    }
}

// ---------------------------------------------------------------------------
// Fused main: one block per (n,b), 512 thr = 8 waves (2 wm x 4 wn), wave 64x64.
// H built by VALU from bf16 coef arrays (b128 LDS reads) + global Hf2, staged
// into swizzled Atile. B (W2T) staged in LDS. MFMA epilogue for layer-3.
// ---------------------------------------------------------------------------
__global__ __launch_bounds__(512) void fused_main(
    const u16* __restrict__ Hf1b, const u16* __restrict__ Hf2,
    const u16* __restrict__ W2T, const float* __restrict__ W1,
    const float* __restrict__ b2, const float* __restrict__ W3,
    const float* __restrict__ b3, const float* __restrict__ positions,
    float* __restrict__ out)
{
    const int n = blockIdx.x, b = blockIdx.y;
    const int tid = threadIdx.x;
    const int base_bn = b * NTOK + n;
    const int wid = tid >> 6, lane = tid & 63, lrow = lane & 15, quad = lane >> 4;

    __shared__ __align__(16) u16 c0b[DD], c1b[DD], s1b[DD];  // bf16 coefs, 3 KB
    __shared__ __align__(16) u16 w3t[16 * 264];              // W3^T padded, 8.25 KB
    __shared__ __align__(16) char mbuf[49152];   // Atile 16K + Btile 32K | gh 34K
    u16* Atile = (u16*)mbuf;                     // [128][64] swizzled
    u16* Btile = (u16*)(mbuf + 16384);           // [256][64] swizzled
    u16* gh    = (u16*)mbuf;                     // [128][136] epilogue

    // ---- phase 0 ----
    {
        int k = tid;  // 512 threads == DD
        c0b[k] = f2bf(W1[(size_t)1024 * DD + k]);
        c1b[k] = f2bf(W1[(size_t)1025 * DD + k]);
        s1b[k] = Hf1b[(size_t)base_bn * DD + k];   // b1 already folded
    }
    {   // w3t: W3 (256x4 fp32) transposed, padded to 16 cols, bf16
        int c = tid & 15, kb = tid >> 4;           // kb 0..31
        int k0w = kb * 8;
        u32 wv[4];
#pragma unroll
        for (int p = 0; p < 4; ++p) {
            int ka = k0w + p * 2;
            u16 va = (c < 4) ? f2bf(W3[ka * 4 + c])       : (u16)0;
            u16 vb = (c < 4) ? f2bf(W3[(ka + 1) * 4 + c]) : (u16)0;
            wv[p] = (u32)va | ((u32)vb << 16);
        }
        *(uint2*)(w3t + c * 264 + k0w)     = make_uint2(wv[0], wv[1]);
        *(uint2*)(w3t + c * 264 + k0w + 4) = make_uint2(wv[2], wv[3]);
    }
    // per-thread position deltas (H-build mapping: m = tid>>2)
    const int mrow = tid >> 2, seg = tid & 3, swA = mrow & 7;
    float px, py;
    {
        float pnx = positions[(size_t)base_bn * 2 + 0];
        float pny = positions[(size_t)base_bn * 2 + 1];
        px = pnx - positions[(size_t)(b * NTOK + mrow) * 2 + 0];
        py = pny - positions[(size_t)(b * NTOK + mrow) * 2 + 1];
    }
    __syncthreads();

    const int wm = wid >> 2, wn = wid & 3;       // main GEMM 2x4 wave grid
    floatx4 acc[4][4];
#pragma unroll
    for (int i = 0; i < 4; ++i)
#pragma unroll
        for (int j = 0; j < 4; ++j) acc[i][j] = (floatx4)(0.0f);

    const u16* hf2p = Hf2 + (size_t)(b * NTOK + mrow) * DD;

    // ---- K loop ----
    for (int kc = 0; kc < 8; ++kc) {
        const int k0 = kc * 64;
        const int kb = k0 + seg * 16;
        {   // stage A: h = relu(hf2 + s1 + px*c0 + py*c1), 16 elems/thread
            uint4 hv = *(const uint4*)(hf2p + kb);
            uint4 hw = *(const uint4*)(hf2p + kb + 8);
            uint4 sv = *(const uint4*)(s1b + kb);
            uint4 sw2 = *(const uint4*)(s1b + kb + 8);
            uint4 av = *(const uint4*)(c0b + kb);
            uint4 aw = *(const uint4*)(c0b + kb + 8);
            uint4 bv = *(const uint4*)(c1b + kb);
            uint4 bw = *(const uint4*)(c1b + kb + 8);
            auto hp = [&](u32 h, u32 s, u32 ca, u32 cb) -> u32 {
                float h0 = bflo(h) + bflo(s) + px * bflo(ca) + py * bflo(cb);
                float h1 = bfhi(h) + bfhi(s) + px * bfhi(ca) + py * bfhi(cb);
                return pkbf(fmaxf(h0, 0.0f), fmaxf(h1, 0.0f));
            };
            uint4 o0 = make_uint4(hp(hv.x, sv.x, av.x, bv.x), hp(hv.y, sv.y, av.y, bv.y),
                                  hp(hv.z, sv.z, av.z, bv.z), hp(hv.w, sv.w, av.w, bv.w));
            uint4 o1 = make_uint4(hp(hw.x, sw2.x, aw.x, bw.x), hp(hw.y, sw2.y, aw.y, bw.y),
                                  hp(hw.z, sw2.z, aw.z, bw.z), hp(hw.w, sw2.w, aw.w, bw.w));
            *(uint4*)(Atile + mrow * 64 + (((seg * 2    ) ^ swA) << 3)) = o0;
            *(uint4*)(Atile + mrow * 64 + (((seg * 2 + 1) ^ swA) << 3)) = o1;
        }
        {   // stage B (W2T): c = tid>>1, 32 elems
            const int c = tid >> 1, sgB = tid & 1, swB = c & 7;
            const uint4* src = (const uint4*)(W2T + (size_t)c * DD + k0 + sgB * 32);
#pragma unroll
            for (int j = 0; j < 4; ++j)
                *(uint4*)(Btile + c * 64 + (((sgB * 4 + j) ^ swB) << 3)) = src[j];
        }
        __syncthreads();
#pragma unroll
        for (int ks = 0; ks < 2; ++ks) {
            const int ch = ks * 4 + quad;
            bf16x8 afr[4], bfr[4];
#pragma unroll
            for (int i = 0; i < 4; ++i) {
                int r = wm * 64 + i * 16 + lrow;
                afr[i] = *(const bf16x8*)(Atile + r * 64 + ((ch ^ (r & 7)) << 3));
            }
#pragma unroll
            for (int j = 0; j < 4; ++j) {
                int c = wn * 64 + j * 16 + lrow;
                bfr[j] = *(const bf16x8*)(Btile + c * 64 + ((ch ^ (c & 7)) << 3));
            }
#pragma unroll
            for (int i = 0; i < 4; ++i)
#pragma unroll
                for (int j = 0; j < 4; ++j)
                    acc[i][j] = __builtin_amdgcn_mfma_f32_16x16x32_bf16(afr[i], bfr[j], acc[i][j], 0, 0, 0);
        }
        __syncthreads();
    }

    // ---- epilogue: relu(acc+b2) -> gh bf16 halves -> layer-3 MFMA ----
    float b2v[4];
#pragma unroll
    for (int j = 0; j < 4; ++j) b2v[j] = b2[wn * 64 + j * 16 + lrow];

    const int smrow = wid * 16;                  // per-wave epilogue row block
    floatx4 acc3 = (floatx4)(0.0f);
#pragma unroll
    for (int half = 0; half < 2; ++half) {
        __syncthreads();
        if ((wn >> 1) == half) {
#pragma unroll
            for (int i = 0; i < 4; ++i)
#pragma unroll
                for (int j = 0; j < 4; ++j)
#pragma unroll
                    for (int r = 0; r < 4; ++r) {
                        int row = wm * 64 + i * 16 + quad * 4 + r;
                        int col = (wn & 1) * 64 + j * 16 + lrow;
                        gh[row * 136 + col] = f2bf(fmaxf(acc[i][j][r] + b2v[j], 0.0f));
                    }
        }
        __syncthreads();
#pragma unroll
        for (int ks = 0; ks < 4; ++ks) {
            bf16x8 gfrag = *(const bf16x8*)(gh + (smrow + lrow) * 136 + ks * 32 + quad * 8);
            bf16x8 wfrag = *(const bf16x8*)(w3t + lrow * 264 + half * 128 + ks * 32 + quad * 8);
            acc3 = __builtin_amdgcn_mfma_f32_16x16x32_bf16(gfrag, wfrag, acc3, 0, 0, 0);
        }
    }
    if (lrow < 4) {
        float bo = b3[lrow];
#pragma unroll
        for (int r = 0; r < 4; ++r) {
            int row = smrow + quad * 4 + r;
            out[(size_t)base_bn * 512 + row * 4 + lrow] = acc3[r] + bo;
        }
    }
}

// ---------------------------------------------------------------------------
extern "C" void kernel_launch(void* const* d_in, const int* in_sizes, int n_in,
                              void* d_out, int out_size, void* d_ws, size_t ws_size,
                              hipStream_t stream)
{
    const float* features  = (const float*)d_in[0];
    const float* positions = (const float*)d_in[1];
    const float* W1 = (const float*)d_in[2];
    const float* b1 = (const float*)d_in[3];
    const float* W2 = (const float*)d_in[4];
    const float* b2 = (const float*)d_in[5];
    const float* W3 = (const float*)d_in[6];
    const float* b3 = (const float*)d_in[7];
    float* out = (float*)d_out;

    char* ws = (char*)d_ws;
    u16* W1aT = (u16*)(ws);                 // 524288 B  (W1bT contiguous after)
    u16* W2T  = (u16*)(ws + 1048576);       // 262144 B
    u16* Hf1b = (u16*)(ws + 1310720);       // 1048576 B
    u16* Hf2  = (u16*)(ws + 2359296);       // 1048576 B (total 3.25 MB)
    u16* W1bT = (u16*)(ws + 524288);

    transpose_k<<<dim3(16, 16, 3), 256, 0, stream>>>(W1, W2, W1aT, W1bT, W2T);
    gemm_layer1<<<dim3(16, 8, 2), 512, 0, stream>>>(features, W1aT, b1, Hf1b, Hf2);
    fused_main<<<dim3(128, 8), 512, 0, stream>>>(Hf1b, Hf2, W2T, W1, b2, W3, b3,
                                                 positions, out);
}